// Round 3
// baseline (781.151 us; speedup 1.0000x reference)
//
#include <hip/hip_runtime.h>
#include <hip/hip_bf16.h>
#include <math.h>

// GCN link prediction, fp32. Self-loops handled analytically:
//   deg[v]  = incount(col==v) + 1 ;  dinv = rsqrt(deg)
//   ts[v]   = (h[v] @ W) * dinv[v]
//   h'[c]   = act( dinv[c]*(sum_{e:col=c} ts[row_e] + ts[c]) + b )
//   score_e = sigmoid(dot(h2[row_e], h2[col_e]))
//
// Fast path: device-built CSR (count -> scan -> fill) + gather aggregation
// (no float atomics; R2 profile showed atomic scatter writes 64B/edge through
// to the memory side = 2x166us). Layer-2 GEMM (16x16) is fused into the
// layer-1 aggregation epilogue via intra-group shuffles.

// ---------------- CSR build ----------------

__global__ void k_count(const int* __restrict__ col, int* __restrict__ cnt, int E) {
    int e = blockIdx.x * 256 + threadIdx.x;
    if (e < E) atomicAdd(&cnt[col[e]], 1);
}

__global__ void k_scanA(const int* __restrict__ cnt, int* __restrict__ partial, int N) {
    __shared__ int s[256];
    int t = threadIdx.x, v = blockIdx.x * 256 + t;
    s[t] = (v < N) ? cnt[v] : 0;
    __syncthreads();
    for (int d = 128; d > 0; d >>= 1) {
        if (t < d) s[t] += s[t + d];
        __syncthreads();
    }
    if (t == 0) partial[blockIdx.x] = s[0];
}

__global__ __launch_bounds__(1024) void k_scanB(const int* __restrict__ partial,
                                                int* __restrict__ blockbase, int NB) {
    __shared__ int s[1024];
    int t = threadIdx.x;
    int v = (t < NB) ? partial[t] : 0;
    s[t] = v;
    __syncthreads();
    for (int d = 1; d < 1024; d <<= 1) {
        int add = (t >= d) ? s[t - d] : 0;
        __syncthreads();
        s[t] += add;
        __syncthreads();
    }
    if (t < NB) blockbase[t] = s[t] - v;   // exclusive scan
}

// start[v] = global exclusive scan of cnt; cursor (ALIASES cnt buffer) = start;
// dinv[v] = rsqrt(cnt+1). Read-before-write per element, block-local chunks.
__global__ void k_scanC(const int* __restrict__ cnt, const int* __restrict__ blockbase,
                        int* __restrict__ start, int* __restrict__ cursor,
                        float* __restrict__ dinv, int N) {
    __shared__ int s[256];
    int t = threadIdx.x, v = blockIdx.x * 256 + t;
    int c = (v < N) ? cnt[v] : 0;
    s[t] = c;
    __syncthreads();
    for (int d = 1; d < 256; d <<= 1) {
        int add = (t >= d) ? s[t - d] : 0;
        __syncthreads();
        s[t] += add;
        __syncthreads();
    }
    if (v < N) {
        int st = blockbase[blockIdx.x] + s[t] - c;
        start[v] = st;
        cursor[v] = st;
        dinv[v] = rsqrtf((float)c + 1.0f);
    }
}

// After this kernel, cursor[v] == end offset for node v.
__global__ void k_fill(const int* __restrict__ row, const int* __restrict__ col,
                       int* __restrict__ cursor, int* __restrict__ rows_sorted, int E) {
    int e = blockIdx.x * 256 + threadIdx.x;
    if (e < E) {
        int p = atomicAdd(&cursor[col[e]], 1);
        rows_sorted[p] = row[e];
    }
}

// ---------------- GEMM1: ts[v] = (x[v] @ W1) * dinv[v] ----------------
// 2 nodes x 16 channels per thread; W1^T staged in LDS, read as wave-uniform
// b128 broadcasts; x read as per-lane float4 (each lane walks its own row,
// L1 serves the 3 follow-up hits per 64B line).
__global__ __launch_bounds__(256) void k_gemm1(
    const float* __restrict__ x, const float* __restrict__ W1,
    const float* __restrict__ dinv, float* __restrict__ ts, int N) {
    __shared__ float wsT[16 * 132];   // wsT[c][k], stride 132 (16B aligned, 2-way max)
    const int tid = threadIdx.x;
    for (int idx = tid; idx < 2048; idx += 256) {
        int k = idx >> 4, c = idx & 15;
        wsT[c * 132 + k] = W1[idx];
    }
    __syncthreads();

    const int base = blockIdx.x * 512;
    const int n0 = base + tid, n1 = base + 256 + tid;
    const bool v0 = n0 < N, v1 = n1 < N;
    const float4* x0 = (const float4*)(x + (size_t)n0 * 128);
    const float4* x1 = (const float4*)(x + (size_t)n1 * 128);

    float acc0[16], acc1[16];
    #pragma unroll
    for (int c = 0; c < 16; ++c) { acc0[c] = 0.f; acc1[c] = 0.f; }

    for (int k4 = 0; k4 < 32; ++k4) {
        float4 a = v0 ? x0[k4] : make_float4(0.f, 0.f, 0.f, 0.f);
        float4 b = v1 ? x1[k4] : make_float4(0.f, 0.f, 0.f, 0.f);
        #pragma unroll
        for (int c = 0; c < 16; ++c) {
            const float4 w = *(const float4*)&wsT[c * 132 + k4 * 4];
            acc0[c] = fmaf(a.x, w.x, fmaf(a.y, w.y, fmaf(a.z, w.z, fmaf(a.w, w.w, acc0[c]))));
            acc1[c] = fmaf(b.x, w.x, fmaf(b.y, w.y, fmaf(b.z, w.z, fmaf(b.w, w.w, acc1[c]))));
        }
    }
    if (v0) {
        float d0 = dinv[n0];
        float4* o = (float4*)(ts + (size_t)n0 * 16);
        #pragma unroll
        for (int q = 0; q < 4; ++q)
            o[q] = make_float4(acc0[4*q] * d0, acc0[4*q+1] * d0, acc0[4*q+2] * d0, acc0[4*q+3] * d0);
    }
    if (v1) {
        float d1 = dinv[n1];
        float4* o = (float4*)(ts + (size_t)n1 * 16);
        #pragma unroll
        for (int q = 0; q < 4; ++q)
            o[q] = make_float4(acc1[4*q] * d1, acc1[4*q+1] * d1, acc1[4*q+2] * d1, acc1[4*q+3] * d1);
    }
}

// ---------------- Aggregation (gather over CSR) ----------------
// 16 lanes per node (lane = channel). Layer 1: + bias + ReLU + fused 16x16
// W2 matmul via intra-group shuffles -> writes ts2 = dinv * (h1 @ W2).
__global__ __launch_bounds__(256) void k_agg1(
    const int* __restrict__ start, const int* __restrict__ endo,
    const int* __restrict__ rows_sorted, const float* __restrict__ ts1,
    const float* __restrict__ dinv, const float* __restrict__ b1,
    const float* __restrict__ W2, float* __restrict__ ts2, int N) {
    __shared__ float w2s[256];
    int t = threadIdx.x;
    w2s[t] = W2[t];
    __syncthreads();

    int v = blockIdx.x * 16 + (t >> 4);
    int c = t & 15;
    int s = start[v], e = endo[v];
    float sum = 0.f;
    for (int i = s; i < e; ++i) {
        int r = rows_sorted[i];
        sum += ts1[(size_t)r * 16 + c];
    }
    float dv = dinv[v];
    float h1 = fmaxf(dv * (sum + ts1[(size_t)v * 16 + c]) + b1[c], 0.f);

    float acc = 0.f;
    #pragma unroll
    for (int k = 0; k < 16; ++k) {
        float hk = __shfl(h1, k, 16);
        acc = fmaf(hk, w2s[k * 16 + c], acc);
    }
    ts2[(size_t)v * 16 + c] = dv * acc;
}

__global__ __launch_bounds__(256) void k_agg2(
    const int* __restrict__ start, const int* __restrict__ endo,
    const int* __restrict__ rows_sorted, const float* __restrict__ ts2,
    const float* __restrict__ dinv, const float* __restrict__ b2,
    float* __restrict__ h2, int N) {
    int t = threadIdx.x;
    int v = blockIdx.x * 16 + (t >> 4);
    int c = t & 15;
    int s = start[v], e = endo[v];
    float sum = 0.f;
    for (int i = s; i < e; ++i) {
        int r = rows_sorted[i];
        sum += ts2[(size_t)r * 16 + c];
    }
    h2[(size_t)v * 16 + c] = dinv[v] * (sum + ts2[(size_t)v * 16 + c]) + b2[c];
}

// ---------------- Edge scores ----------------
__global__ void k_score(const int* __restrict__ row, const int* __restrict__ col,
                        const float* __restrict__ h2, float* __restrict__ out, int E) {
    int e = blockIdx.x * 256 + threadIdx.x;
    if (e < E) {
        const float4* a = (const float4*)(h2 + (size_t)row[e] * 16);
        const float4* b = (const float4*)(h2 + (size_t)col[e] * 16);
        float d = 0.f;
        #pragma unroll
        for (int i = 0; i < 4; ++i) {
            float4 u = a[i], v = b[i];
            d += u.x * v.x + u.y * v.y + u.z * v.z + u.w * v.w;
        }
        out[e] = 1.0f / (1.0f + __expf(-d));
    }
}

// ---------------- Fallback (R2 atomic path) kernels ----------------
__global__ void k_countf(const int* __restrict__ col, float* __restrict__ deg, int E) {
    int e = blockIdx.x * 256 + threadIdx.x;
    if (e < E) atomicAdd(&deg[col[e]], 1.0f);
}
__global__ void k_dinvf(float* __restrict__ dinv, int N) {
    int v = blockIdx.x * 256 + threadIdx.x;
    if (v < N) dinv[v] = rsqrtf(dinv[v] + 1.0f);
}
__global__ void k_scatter(const int* __restrict__ row, const int* __restrict__ col,
                          const float* __restrict__ ts, float* __restrict__ acc, int E) {
    int g = blockIdx.x * 256 + threadIdx.x;
    int e = g >> 4, c = g & 15;
    if (e < E) atomicAdd(&acc[(size_t)col[e] * 16 + c], ts[(size_t)row[e] * 16 + c]);
}
__global__ void k_finalize(float* __restrict__ acc, const float* __restrict__ ts,
                           const float* __restrict__ dinv, const float* __restrict__ b,
                           int N, int relu) {
    int g = blockIdx.x * 256 + threadIdx.x;
    int v = g >> 4, c = g & 15;
    if (v < N) {
        float h = dinv[v] * (acc[g] + ts[g]) + b[c];
        if (relu) h = fmaxf(h, 0.f);
        acc[g] = h;
    }
}
__global__ __launch_bounds__(256) void k_gemm2f(
    const float* __restrict__ h1, const float* __restrict__ W2,
    const float* __restrict__ dinv, float* __restrict__ ts2, int N) {
    __shared__ float hs[16 * 17];
    __shared__ float ws[256];
    const int tid = threadIdx.x;
    const int base = blockIdx.x * 16;
    if (tid < 64) ((float4*)ws)[tid] = ((const float4*)W2)[tid];
    if (tid >= 64 && tid < 128) {
        int t2 = tid - 64;
        float4 v4 = ((const float4*)(h1 + (size_t)base * 16))[t2];
        float* d = &hs[(t2 >> 2) * 17 + (t2 & 3) * 4];
        d[0] = v4.x; d[1] = v4.y; d[2] = v4.z; d[3] = v4.w;
    }
    __syncthreads();
    const int r = tid >> 4, c = tid & 15;
    float acc = 0.f;
    #pragma unroll
    for (int k = 0; k < 16; ++k) acc = fmaf(hs[r * 17 + k], ws[k * 16 + c], acc);
    ts2[(size_t)(base + r) * 16 + c] = acc * dinv[base + r];
}

extern "C" void kernel_launch(void* const* d_in, const int* in_sizes, int n_in,
                              void* d_out, int out_size, void* d_ws, size_t ws_size,
                              hipStream_t stream) {
    const float* x  = (const float*)d_in[0];
    const int*   ei = (const int*)d_in[1];
    const float* W1 = (const float*)d_in[2];
    const float* b1 = (const float*)d_in[3];
    const float* W2 = (const float*)d_in[4];
    const float* b2 = (const float*)d_in[5];

    const int N = in_sizes[0] / 128;   // 100000
    const int E = in_sizes[1] / 2;     // 3200000
    const int* row = ei;
    const int* col = ei + E;
    float* out = (float*)d_out;

    const int NB = (N + 255) / 256;    // scan blocks (391 <= 1024)

    // CSR-path workspace layout
    char* ws = (char*)d_ws;
    size_t off = 0;
    float* dinv = (float*)(ws + off); off += (size_t)N * 4;
    float* ts1  = (float*)(ws + off); off += (size_t)N * 64;   // also h2 later
    float* ts2  = (float*)(ws + off); off += (size_t)N * 64;
    int* cnt    = (int*)(ws + off);   off += (size_t)N * 4;    // aliased as cursor
    int* start  = (int*)(ws + off);   off += (size_t)N * 4;
    int* partial   = (int*)(ws + off); off += 1024 * 4;
    int* blockbase = (int*)(ws + off); off += 1024 * 4;
    int* rows_sorted = (int*)(ws + off); off += (size_t)E * 4;
    const size_t csr_need = off;

    if (ws_size >= csr_need && NB <= 1024) {
        hipMemsetAsync(cnt, 0, (size_t)N * 4, stream);
        k_count<<<(E + 255) / 256, 256, 0, stream>>>(col, cnt, E);
        k_scanA<<<NB, 256, 0, stream>>>(cnt, partial, N);
        k_scanB<<<1, 1024, 0, stream>>>(partial, blockbase, NB);
        k_scanC<<<NB, 256, 0, stream>>>(cnt, blockbase, start, cnt /*cursor*/, dinv, N);
        k_fill<<<(E + 255) / 256, 256, 0, stream>>>(row, col, cnt /*cursor*/, rows_sorted, E);
        k_gemm1<<<(N + 511) / 512, 256, 0, stream>>>(x, W1, dinv, ts1, N);
        k_agg1<<<N / 16, 256, 0, stream>>>(start, cnt /*end*/, rows_sorted, ts1, dinv, b1, W2, ts2, N);
        k_agg2<<<N / 16, 256, 0, stream>>>(start, cnt /*end*/, rows_sorted, ts2, dinv, b2, ts1 /*h2*/, N);
        k_score<<<(E + 255) / 256, 256, 0, stream>>>(row, col, ts1, out, E);
    } else {
        // R2 atomic fallback: dinv | ts1 | ts2(acc) = 132N bytes
        hipMemsetAsync(dinv, 0, (size_t)N * 4, stream);
        hipMemsetAsync(ts2, 0, (size_t)N * 64, stream);
        k_countf<<<(E + 255) / 256, 256, 0, stream>>>(col, dinv, E);
        k_dinvf<<<(N + 255) / 256, 256, 0, stream>>>(dinv, N);
        k_gemm1<<<(N + 511) / 512, 256, 0, stream>>>(x, W1, dinv, ts1, N);
        k_scatter<<<(E * 16) / 256, 256, 0, stream>>>(row, col, ts1, ts2, E);
        k_finalize<<<(N * 16 + 255) / 256, 256, 0, stream>>>(ts2, ts1, dinv, b1, N, 1);
        k_gemm2f<<<N / 16, 256, 0, stream>>>(ts2, W2, dinv, ts1, N);
        hipMemsetAsync(ts2, 0, (size_t)N * 64, stream);
        k_scatter<<<(E * 16) / 256, 256, 0, stream>>>(row, col, ts1, ts2, E);
        k_finalize<<<(N * 16 + 255) / 256, 256, 0, stream>>>(ts2, ts1, dinv, b2, N, 0);
        k_score<<<(E + 255) / 256, 256, 0, stream>>>(row, col, ts2, out, E);
    }
}